// Round 9
// baseline (240.768 us; speedup 1.0000x reference)
//
#include <hip/hip_runtime.h>
#include <hip/hip_bf16.h>

#define BSZ 2
#define SEQ 2048
#define DIMN 1024
#define NH 16
#define DH 64
#define LOG2E 1.4426950408889634f

typedef unsigned short ushort_t;
typedef __attribute__((ext_vector_type(8))) short short8;
typedef __attribute__((ext_vector_type(4))) float float4v;

__device__ __forceinline__ ushort_t f2bf(float f) {
    union { float f; unsigned int u; } c; c.f = f;
    return (ushort_t)((c.u + 0x8000u) >> 16);
}
__device__ __forceinline__ unsigned int pkbf(float a, float b) {
    __hip_bfloat162 h = __float22bfloat162_rn(make_float2(a, b));
    unsigned int u; __builtin_memcpy(&u, &h, 4); return u;
}
__device__ __forceinline__ unsigned int pkbf_asm(float a, float b) {
    unsigned int d;
    asm("v_cvt_pk_bf16_f32 %0, %1, %2" : "=v"(d) : "v"(a), "v"(b));
    return d;
}
__device__ __forceinline__ float exp2_raw(float x) {
    float d; asm("v_exp_f32 %0, %1" : "=v"(d) : "v"(x)); return d;
}
__device__ __forceinline__ float max3f(float a, float b, float c) {
    float d; asm("v_max3_f32 %0, %1, %2, %3" : "=v"(d) : "v"(a), "v"(b), "v"(c)); return d;
}
__device__ __forceinline__ void gld16(const ushort_t* g, ushort_t* l) {
    __builtin_amdgcn_global_load_lds(
        (const __attribute__((address_space(1))) unsigned int*)g,
        (__attribute__((address_space(3))) unsigned int*)l, 16, 0, 0);
}

// ---------------- weight pre-convert f32 -> bf16 (4 matrices only, 1Mi each) --------
__global__ __launch_bounds__(256) void cvt_w4(
    const float* __restrict__ w0, const float* __restrict__ w1,
    const float* __restrict__ w2, const float* __restrict__ w3,
    ushort_t* __restrict__ o0, ushort_t* __restrict__ o1,
    ushort_t* __restrict__ o2, ushort_t* __restrict__ o3)
{
    const float* s; ushort_t* d;
    switch (blockIdx.y) {
        case 0: s = w0; d = o0; break;
        case 1: s = w1; d = o1; break;
        case 2: s = w2; d = o2; break;
        default: s = w3; d = o3; break;
    }
    int i = (blockIdx.x * 256 + threadIdx.x) * 4;
    float4v v = *(const float4v*)(s + i);
    uint2 o; o.x = pkbf(v[0], v[1]); o.y = pkbf(v[2], v[3]);
    *(uint2*)(d + i) = o;
}

// ---------------- QKV GEMM (hybrid): A = f32 X reg-staged + cvt, B = bf16 gld16 -----
// R9: X conversion folded into A-staging (removes Xb write + re-read + 2/3 of the
// cvt kernel). A: f32 float4x2 -> pkbf -> ds_write_b128 to the XOR-swizzled
// stride-64 layout (write-side swizzle explicit; read side unchanged — both-sides
// rule). B: gld16 with pre-swizzled global source (proven). 2-barrier K-loop.
__global__ __launch_bounds__(256) void gemm_qkv_hyb(
    const float* __restrict__ xq, const float* __restrict__ xk, const float* __restrict__ xv,
    const ushort_t* __restrict__ Wq, const ushort_t* __restrict__ Wk, const ushort_t* __restrict__ Wv,
    const float* __restrict__ qb, const float* __restrict__ kb, const float* __restrict__ vb,
    ushort_t* __restrict__ Qp, ushort_t* __restrict__ Kp, ushort_t* __restrict__ VpT)
{
    __shared__ __align__(16) ushort_t As[128 * 64];
    __shared__ __align__(16) ushort_t Bs[128 * 64];
    const int tid  = threadIdx.x;
    const int lane = tid & 63;
    const int w    = tid >> 6;
    const int wm   = w >> 1, wn = w & 1;
    const int quad = lane >> 4;
    const int l16  = lane & 15;
    const int sw   = l16 & 7;
    const int mBase = blockIdx.y * 128;
    const int nGlob = blockIdx.x * 128;
    const int z     = nGlob >> 10;
    const int nBase = nGlob & 1023;
    const float*    A    = (z == 0) ? xq : (z == 1) ? xk : xv;
    const ushort_t* W    = (z == 0) ? Wq : (z == 1) ? Wk : Wv;
    const float*    bias = (z == 0) ? qb : (z == 1) ? kb : vb;

    const int srow = tid >> 3;   // 0..31 (B staging row within 32-row group)
    const int sc   = tid & 7;    // 16B chunk

    float4v acc[4][4];
    const float4v z4 = {0.f, 0.f, 0.f, 0.f};
#pragma unroll
    for (int i = 0; i < 4; ++i)
#pragma unroll
        for (int j = 0; j < 4; ++j) acc[i][j] = z4;

    for (int k0 = 0; k0 < 1024; k0 += 64) {
        // ---- B: bf16 weights via gld16, pre-swizzled source (proven pattern) ----
#pragma unroll
        for (int itq = 0; itq < 4; ++itq) {
            int row = itq * 32 + srow;
            int colsw = (sc ^ (row & 7)) * 8;
            gld16(W + (size_t)(nBase + row) * 1024 + k0 + colsw, &Bs[(itq * 32 + w * 8) * 64]);
        }
        // ---- A: f32 X, load + convert + swizzled ds_write (write-side swizzle) ----
#pragma unroll
        for (int it = 0; it < 4; ++it) {
            int c = it * 256 + tid, row = c >> 3, col8 = c & 7;
            const float* g = A + (size_t)(mBase + row) * 1024 + k0 + col8 * 8;
            float4v a0 = *(const float4v*)g;
            float4v a1 = *(const float4v*)(g + 4);
            uint4 ua;
            ua.x = pkbf(a0[0], a0[1]); ua.y = pkbf(a0[2], a0[3]);
            ua.z = pkbf(a1[0], a1[1]); ua.w = pkbf(a1[2], a1[3]);
            *(uint4*)&As[row * 64 + ((col8 ^ (row & 7)) * 8)] = ua;
        }
        __syncthreads();   // drains vmcnt (B gld16) + lgkmcnt (A ds_write)

#pragma unroll
        for (int ksub = 0; ksub < 2; ++ksub) {
            short8 af[4], bf[4];
#pragma unroll
            for (int mt = 0; mt < 4; ++mt)
                af[mt] = *(const short8*)&As[(wm * 64 + mt * 16 + l16) * 64 + ((ksub * 4 + quad) ^ sw) * 8];
#pragma unroll
            for (int nt = 0; nt < 4; ++nt)
                bf[nt] = *(const short8*)&Bs[(wn * 64 + nt * 16 + l16) * 64 + ((ksub * 4 + quad) ^ sw) * 8];
#pragma unroll
            for (int mt = 0; mt < 4; ++mt)
#pragma unroll
                for (int nt = 0; nt < 4; ++nt)
                    acc[mt][nt] = __builtin_amdgcn_mfma_f32_16x16x32_bf16(af[mt], bf[nt], acc[mt][nt], 0, 0, 0);
        }
        __syncthreads();   // reads done before next iter's staging overwrites
    }

    const float scale = (z == 0) ? 0.125f * LOG2E : 1.0f;
    if (z < 2) {
        ushort_t* C = (z == 0) ? Qp : Kp;
#pragma unroll
        for (int mt = 0; mt < 4; ++mt)
#pragma unroll
            for (int nt = 0; nt < 4; ++nt) {
                int colg = nBase + wn * 64 + nt * 16 + l16;
                float bv = bias[colg];
#pragma unroll
                for (int r = 0; r < 4; ++r) {
                    int rowg = mBase + wm * 64 + mt * 16 + quad * 4 + r;
                    C[(size_t)rowg * 1024 + colg] = f2bf((acc[mt][nt][r] + bv) * scale);
                }
            }
    } else {
#pragma unroll
        for (int mt = 0; mt < 4; ++mt)
#pragma unroll
            for (int nt = 0; nt < 4; ++nt) {
                int n = nBase + wn * 64 + nt * 16 + l16;
                int hh = n >> 6, d = n & 63;
                float bv = bias[n];
                int rowg = mBase + wm * 64 + mt * 16 + quad * 4;
                int b = rowg >> 11, s = rowg & 2047;
                uint2 pk;
                pk.x = pkbf(acc[mt][nt][0] + bv, acc[mt][nt][1] + bv);
                pk.y = pkbf(acc[mt][nt][2] + bv, acc[mt][nt][3] + bv);
                *(uint2*)&VpT[(((size_t)(b * 16 + hh) * 64 + d) << 11) + s] = pk;
            }
    }
}

// ---------------- O GEMM: 128x64, BK=64 — gld16 + swizzled LDS (R4-proven) ----------
__global__ __launch_bounds__(256) void gemm_o(
    const ushort_t* __restrict__ A, const ushort_t* __restrict__ W,
    const float* __restrict__ bias, float* __restrict__ C)
{
    __shared__ __align__(16) ushort_t As[128 * 64];
    __shared__ __align__(16) ushort_t Bs[64 * 64];
    const int tid  = threadIdx.x;
    const int lane = tid & 63;
    const int w    = tid >> 6;
    const int wm   = w & 1, wn = w >> 1;
    const int quad = lane >> 4;
    const int l16  = lane & 15;
    const int sw   = l16 & 7;
    const int mBase = blockIdx.y * 128;
    const int nBase = blockIdx.x * 64;
    const int srow = tid >> 3;   // 0..31
    const int sc   = tid & 7;

    float4v acc[4][2];
    const float4v z4 = {0.f, 0.f, 0.f, 0.f};
#pragma unroll
    for (int mt = 0; mt < 4; ++mt)
#pragma unroll
        for (int nt = 0; nt < 2; ++nt) acc[mt][nt] = z4;

    for (int k0 = 0; k0 < 1024; k0 += 64) {
#pragma unroll
        for (int itq = 0; itq < 4; ++itq) {
            int row = itq * 32 + srow;
            gld16(A + (size_t)(mBase + row) * 1024 + k0 + ((sc ^ (row & 7)) * 8),
                  &As[(itq * 32 + w * 8) * 64]);
        }
#pragma unroll
        for (int itq = 0; itq < 2; ++itq) {
            int row = itq * 32 + srow;
            gld16(W + (size_t)(nBase + row) * 1024 + k0 + ((sc ^ (row & 7)) * 8),
                  &Bs[(itq * 32 + w * 8) * 64]);
        }
        __syncthreads();

#pragma unroll
        for (int ksub = 0; ksub < 2; ++ksub) {
            short8 af[4], bf[2];
#pragma unroll
            for (int mt = 0; mt < 4; ++mt)
                af[mt] = *(const short8*)&As[(wm * 64 + mt * 16 + l16) * 64 + ((ksub * 4 + quad) ^ sw) * 8];
#pragma unroll
            for (int nt = 0; nt < 2; ++nt)
                bf[nt] = *(const short8*)&Bs[(wn * 32 + nt * 16 + l16) * 64 + ((ksub * 4 + quad) ^ sw) * 8];
#pragma unroll
            for (int mt = 0; mt < 4; ++mt)
#pragma unroll
                for (int nt = 0; nt < 2; ++nt)
                    acc[mt][nt] = __builtin_amdgcn_mfma_f32_16x16x32_bf16(af[mt], bf[nt], acc[mt][nt], 0, 0, 0);
        }
        __syncthreads();
    }

#pragma unroll
    for (int mt = 0; mt < 4; ++mt)
#pragma unroll
        for (int nt = 0; nt < 2; ++nt) {
            int colg = nBase + wn * 32 + nt * 16 + l16;
            float bv = bias[colg];
#pragma unroll
            for (int r = 0; r < 4; ++r) {
                int rowg = mBase + wm * 64 + mt * 16 + quad * 4 + r;
                C[(size_t)rowg * 1024 + colg] = acc[mt][nt][r] + bv;
            }
        }
}

// ---------------- fused flash attention: R7-exact (proven 53.7 us) ------------------
// T15 software pipeline — per iter: prefetch(t+1); [QK(t) + PV(t-1)] as one MFMA
// cluster; softmax(t); pack P(t). P ping-pong in LDS; V triple-buffered with
// rotating pointers; single barrier per tile; defer-max; C-init -m bias.
__global__ __launch_bounds__(512) void attn_kernel(
    const ushort_t* __restrict__ Qp, const ushort_t* __restrict__ Kp,
    const ushort_t* __restrict__ VpT, const int* __restrict__ mask,
    ushort_t* __restrict__ Cp)
{
    __shared__ __align__(16) ushort_t Ps[2][128 * 64]; // P ping-pong; Ps[0] = Q staging
    __shared__ __align__(16) ushort_t Ks[2][64 * 64];  // K double buffer
    __shared__ __align__(16) ushort_t Vt[3][64 * 64];  // V^T triple buffer [dim][key]
    __shared__ int s_mok[8];

    const int tid  = threadIdx.x;
    const int lane = tid & 63;
    const int w    = tid >> 6;          // 0..7
    const int quad = lane >> 4;
    const int l16  = lane & 15;
    const int sw   = l16 & 7;           // per-lane XOR swizzle key for reads
    const int b    = blockIdx.x >> 4;
    const int h    = blockIdx.x & 15;
    const int q0   = blockIdx.y * 128;

    const int srow = tid >> 3;          // staging row 0..63
    const int sc   = tid & 7;           // staging 16B chunk 0..7
    const int gsc  = (sc ^ (srow & 7)) * 8;  // pre-swizzled global source col (elems)
    const ushort_t* Vbase = VpT + ((size_t)(b * 16 + h) * 64) * 2048;
    const ushort_t* Kbase = Kp + (size_t)b * SEQ * DIMN + h * DH;
    const ushort_t* Qbase = Qp + (size_t)(b * SEQ + q0) * DIMN + h * DH;

    // block-level mask scan: is the whole key row unmasked?
    {
        int m0 = mask[b * SEQ + tid];
        int m1 = mask[b * SEQ + 512 + tid];
        int m2 = mask[b * SEQ + 1024 + tid];
        int m3 = mask[b * SEQ + 1536 + tid];
        int ok = __all((m0 != 0) & (m1 != 0) & (m2 != 0) & (m3 != 0));
        if (lane == 0) s_mok[w] = ok;
    }

    // stage Q (128x64) into Ps[0]
#pragma unroll
    for (int it2 = 0; it2 < 2; ++it2) {
        int row = it2 * 64 + srow;
        gld16(Qbase + (size_t)row * DIMN + ((sc ^ (row & 7)) * 8),
              &Ps[0][(it2 * 64 + w * 8) * 64]);
    }
    // K/V tile 0
    gld16(Kbase + (size_t)srow * DIMN + gsc, &Ks[0][w * 512]);
    gld16(Vbase + (size_t)srow * 2048 + gsc, &Vt[0][w * 512]);
    __syncthreads();   // drains vmcnt: Q/K0/V0 in LDS, s_mok visible

    const int mall = s_mok[0] & s_mok[1] & s_mok[2] & s_mok[3]
                   & s_mok[4] & s_mok[5] & s_mok[6] & s_mok[7];

    short8 bq[2];
#pragma unroll
    for (int ks = 0; ks < 2; ++ks)
        bq[ks] = *(const short8*)&Ps[0][(w * 16 + l16) * 64 + ((4 * ks + quad) ^ sw) * 8];

    const float4v z4 = {0.f, 0.f, 0.f, 0.f};
    float4v Oacc[4];   // O^T: [dim vt*16+quad*4+r][qrow l16]
#pragma unroll
    for (int vt = 0; vt < 4; ++vt) Oacc[vt] = z4;
    float4v Lacc = z4;
    float mrow = 0.0f;        // per-qrow running max (log2 domain)
    float4v mneg4 = z4;       // = {-mrow}; C-init of QK MFMA supplies the -m bias

    short8 ones;
#pragma unroll
    for (int j = 0; j < 8; ++j) ones[j] = (short)0x3F80;

    const int NT = SEQ / 64;
    const int prow = (w * 16 + l16) * 64;   // wave-private P/V row base

    // ---------------- peeled iter 0: QK(0) + softmax(0) + pack, no PV ----------------
    {
        gld16(Kbase + (size_t)(64 + srow) * DIMN + gsc, &Ks[1][w * 512]);
        gld16(Vbase + (size_t)srow * 2048 + 64 + gsc, &Vt[1][w * 512]);

        float4v Sv[4];
        __builtin_amdgcn_s_setprio(1);
#pragma unroll
        for (int kt = 0; kt < 4; ++kt) {
            short8 ak = *(const short8*)&Ks[0][(kt * 16 + l16) * 64 + (quad ^ sw) * 8];
            Sv[kt] = __builtin_amdgcn_mfma_f32_16x16x32_bf16(ak, bq[0], mneg4, 0, 0, 0);
        }
#pragma unroll
        for (int kt = 0; kt < 4; ++kt) {
            short8 ak = *(const short8*)&Ks[0][(kt * 16 + l16) * 64 + ((4 + quad) ^ sw) * 8];
            Sv[kt] = __builtin_amdgcn_mfma_f32_16x16x32_bf16(ak, bq[1], Sv[kt], 0, 0, 0);
        }
        __builtin_amdgcn_s_setprio(0);

        if (!mall) {
#pragma unroll
            for (int kt = 0; kt < 4; ++kt) {
                int4 mv = *(const int4*)(mask + b * SEQ + kt * 16 + quad * 4);
#pragma unroll
                for (int r = 0; r < 4; ++r) {
                    int m = (r == 0) ? mv.x : (r == 1) ? mv.y : (r == 2) ? mv.z : mv.w;
                    Sv[kt][r] += (m == 0) ? -1e30f : 0.0f;
                }
            }
        }

        float a0 = max3f(Sv[0][0], Sv[0][1], Sv[0][2]);
        float a1 = max3f(Sv[0][3], Sv[1][0], Sv[1][1]);
        float a2 = max3f(Sv[1][2], Sv[1][3], Sv[2][0]);
        float a3 = max3f(Sv[2][1], Sv[2][2], Sv[2][3]);
        float a4 = max3f(Sv[3][0], Sv[3][1], Sv[3][2]);
        float b0 = max3f(a0, a1, Sv[3][3]);
        float b1 = max3f(a2, a3, a4);
        float mx = fmaxf(b0, b1);
        mx = fmaxf(mx, __shfl_xor(mx, 16));
        mx = fmaxf(mx, __shfl_xor(mx, 32));
        if (!__all(mx <= 8.0f)) {
            float d = fmaxf(mx, 0.0f);
            float alpha = exp2_raw(-d);
            mrow += d;
#pragma unroll
            for (int vt = 0; vt < 4; ++vt) Oacc[vt] *= alpha;
            Lacc *= alpha;
#pragma unroll
            for (int kt = 0; kt < 4; ++kt)
#pragma unroll
                for (int r = 0; r < 4; ++r) Sv[kt][r] -= d;
            mneg4[0] = -mrow; mneg4[1] = -mrow; mneg4[2] = -mrow; mneg4[3] = -mrow;
        }
#pragma unroll
        for (int kt = 0; kt < 4; ++kt)
#pragma unroll
            for (int r = 0; r < 4; ++r) Sv[kt][r] = exp2_raw(Sv[kt][r]);

#pragma unroll
        for (int kt = 0; kt < 4; ++kt) {
            uint2 pk;
            pk.x = pkbf_asm(Sv[kt][0], Sv[kt][1]);
            pk.y = pkbf_asm(Sv[kt][2], Sv[kt][3]);
            int chunk = (2 * kt + (quad >> 1)) ^ sw;
            *(uint2*)&Ps[0][prow + chunk * 8 + (quad & 1) * 4] = pk;
        }
        __syncthreads();   // drains K1/V1 prefetch; P(0) visible (wave-private anyway)
    }

    // rotating V pointers: at loop iter t, vRd=V(t-1), vCur=V(t), vWr=slot for V(t+1)
    ushort_t* vRd  = Vt[0];
    ushort_t* vCur = Vt[1];
    ushort_t* vWr  = Vt[2];

#pragma unroll 2
    for (int t = 1; t < NT; ++t) {
        const int kt0 = t * 64;

        // prefetch tile t+1
        if (t + 1 < NT) {
            gld16(Kbase + (size_t)(kt0 + 64 + srow) * DIMN + gsc, &Ks[(t + 1) & 1][w * 512]);
            gld16(Vbase + (size_t)srow * 2048 + kt0 + 64 + gsc, vWr + w * 512);
        }

        // ---- fused MFMA cluster: QK(t) then PV(t-1) ----
        float4v Sv[4];
        __builtin_amdgcn_s_setprio(1);
#pragma unroll
        for (int kt = 0; kt < 4; ++kt) {
            short8 ak = *(const short8*)&Ks[t & 1][(kt * 16 + l16) * 64 + (quad ^ sw) * 8];
            Sv[kt] = __builtin_amdgcn_mfma_f32_16x16x32_bf16(ak, bq[0], mneg4, 0, 0, 0);
        }
#pragma unroll
        for (int kt = 0; kt < 4; ++kt) {
            short8 ak = *(const short8*)&Ks[t & 1][(kt * 16 + l16) * 64 + ((4 + quad) ^ sw) * 8];
            Sv[kt] = __builtin_amdgcn_mfma_f32_16x16x32_bf16(ak, bq[1], Sv[kt], 0, 0, 0);
        }
        // PV(t-1): P from Ps[(t-1)&1], V from vRd (= V(t-1))
#pragma unroll
        for (int ks = 0; ks < 2; ++ks) {
            short8 bp = *(const short8*)&Ps[(t - 1) & 1][prow + ((4 * ks + quad) ^ sw) * 8];
            Lacc = __builtin_amdgcn_mfma_f32_16x16x32_bf16(ones, bp, Lacc, 0, 0, 0);
#pragma unroll
            for (int vt = 0; vt < 4; ++vt) {
                short8 av = *(const short8*)(vRd + (vt * 16 + l16) * 64 + ((4 * ks + quad) ^ sw) * 8);
                Oacc[vt] = __builtin_amdgcn_mfma_f32_16x16x32_bf16(av, bp, Oacc[vt], 0, 0, 0);
            }
        }
        __builtin_amdgcn_s_setprio(0);

        // additive mask (rare path)
        if (!mall) {
#pragma unroll
            for (int kt = 0; kt < 4; ++kt) {
                int4 mv = *(const int4*)(mask + b * SEQ + kt0 + kt * 16 + quad * 4);
#pragma unroll
                for (int r = 0; r < 4; ++r) {
                    int m = (r == 0) ? mv.x : (r == 1) ? mv.y : (r == 2) ? mv.z : mv.w;
                    Sv[kt][r] += (m == 0) ? -1e30f : 0.0f;
                }
            }
        }

        // softmax(t) — O already holds PV(0..t-1), so rescale here is correct
        float a0 = max3f(Sv[0][0], Sv[0][1], Sv[0][2]);
        float a1 = max3f(Sv[0][3], Sv[1][0], Sv[1][1]);
        float a2 = max3f(Sv[1][2], Sv[1][3], Sv[2][0]);
        float a3 = max3f(Sv[2][1], Sv[2][2], Sv[2][3]);
        float a4 = max3f(Sv[3][0], Sv[3][1], Sv[3][2]);
        float b0 = max3f(a0, a1, Sv[3][3]);
        float b1 = max3f(a2, a3, a4);
        float mx = fmaxf(b0, b1);
        mx = fmaxf(mx, __shfl_xor(mx, 16));
        mx = fmaxf(mx, __shfl_xor(mx, 32));
        if (!__all(mx <= 8.0f)) {
            float d = fmaxf(mx, 0.0f);
            float alpha = exp2_raw(-d);
            mrow += d;
#pragma unroll
            for (int vt = 0; vt < 4; ++vt) Oacc[vt] *= alpha;
            Lacc *= alpha;
#pragma unroll
            for (int kt = 0; kt < 4; ++kt)
#pragma unroll
                for (int r = 0; r < 4; ++r) Sv[kt][r] -= d;
            mneg4[0] = -mrow; mneg4[1] = -mrow; mneg4[2] = -mrow; mneg4[3] = -mrow;
        }
#pragma unroll
        for (int kt = 0; kt < 4; ++kt)
#pragma unroll
            for (int r = 0; r < 4; ++r) Sv[kt][r] = exp2_raw(Sv[kt][r]);

        // pack P(t) -> Ps[t&1] (wave-private rows; PV next iter reads it)
#pragma unroll
        for (int kt = 0; kt < 4; ++kt) {
            uint2 pk;
            pk.x = pkbf_asm(Sv[kt][0], Sv[kt][1]);
            pk.y = pkbf_asm(Sv[kt][2], Sv[kt][3]);
            int chunk = (2 * kt + (quad >> 1)) ^ sw;
            *(uint2*)&Ps[t & 1][prow + chunk * 8 + (quad & 1) * 4] = pk;
        }

        __syncthreads();   // drains prefetch vmcnt + separates K/V buffer roles

        // rotate V buffers
        ushort_t* tmp = vRd; vRd = vCur; vCur = vWr; vWr = tmp;
    }

    // ---------------- epilogue: PV(NT-1) then normalize + store ----------------------
#pragma unroll
    for (int ks = 0; ks < 2; ++ks) {
        short8 bp = *(const short8*)&Ps[(NT - 1) & 1][prow + ((4 * ks + quad) ^ sw) * 8];
        Lacc = __builtin_amdgcn_mfma_f32_16x16x32_bf16(ones, bp, Lacc, 0, 0, 0);
#pragma unroll
        for (int vt = 0; vt < 4; ++vt) {
            short8 av = *(const short8*)(vRd + (vt * 16 + l16) * 64 + ((4 * ks + quad) ^ sw) * 8);
            Oacc[vt] = __builtin_amdgcn_mfma_f32_16x16x32_bf16(av, bp, Oacc[vt], 0, 0, 0);
        }
    }

    float inv = 1.0f / Lacc[0];
    int row = q0 + w * 16 + l16;
#pragma unroll
    for (int vt = 0; vt < 4; ++vt) {
        uint2 pk;
        pk.x = pkbf_asm(Oacc[vt][0] * inv, Oacc[vt][1] * inv);
        pk.y = pkbf_asm(Oacc[vt][2] * inv, Oacc[vt][3] * inv);
        *(uint2*)&Cp[(size_t)(b * SEQ + row) * DIMN + h * DH + vt * 16 + quad * 4] = pk;
    }
}

extern "C" void kernel_launch(void* const* d_in, const int* in_sizes, int n_in,
                              void* d_out, int out_size, void* d_ws, size_t ws_size,
                              hipStream_t stream) {
    const float* x_q = (const float*)d_in[0];
    const float* x_k = (const float*)d_in[1];
    const float* x_v = (const float*)d_in[2];
    const int*   msk = (const int*)d_in[3];
    const float* q_w = (const float*)d_in[4];
    const float* q_b = (const float*)d_in[5];
    const float* k_w = (const float*)d_in[6];
    const float* k_b = (const float*)d_in[7];
    const float* v_w = (const float*)d_in[8];
    const float* v_b = (const float*)d_in[9];
    const float* o_w = (const float*)d_in[10];
    const float* o_b = (const float*)d_in[11];
    float* out = (float*)d_out;

    const size_t NEL = (size_t)BSZ * SEQ * DIMN;   // 4 Mi
    const size_t WEL = (size_t)DIMN * DIMN;        // 1 Mi
    // layout: Qp | Kp | VpT | Wq Wk Wv Wo  (24 MiB; no Xb — X converted in-GEMM)
    ushort_t* Qp  = (ushort_t*)d_ws;
    ushort_t* Kp  = Qp + NEL;
    ushort_t* VpT = Kp + NEL;
    ushort_t* Wq  = VpT + NEL;
    ushort_t* Wk  = Wq + WEL;
    ushort_t* Wv  = Wk + WEL;
    ushort_t* Wo  = Wv + WEL;
    ushort_t* Cp  = Qp;   // aliases Qp (read-before-write, per-block disjoint regions)

    cvt_w4<<<dim3(WEL / 1024, 4), 256, 0, stream>>>(q_w, k_w, v_w, o_w, Wq, Wk, Wv, Wo);
    gemm_qkv_hyb<<<dim3(24, 32), 256, 0, stream>>>(x_q, x_k, x_v, Wq, Wk, Wv,
                                                   q_b, k_b, v_b, Qp, Kp, VpT);
    attn_kernel<<<dim3(BSZ * NH, SEQ / 128), 512, 0, stream>>>(Qp, Kp, VpT, msk, Cp);
    gemm_o<<<dim3(16, 32), 256, 0, stream>>>(Cp, Wo, o_b, out);
}

// Round 10
// 224.595 us; speedup vs baseline: 1.0720x; 1.0720x over previous
//
#include <hip/hip_runtime.h>
#include <hip/hip_bf16.h>

#define BSZ 2
#define SEQ 2048
#define DIMN 1024
#define NH 16
#define DH 64
#define LOG2E 1.4426950408889634f

typedef unsigned short ushort_t;
typedef __attribute__((ext_vector_type(8))) short short8;
typedef __attribute__((ext_vector_type(4))) float float4v;

__device__ __forceinline__ ushort_t f2bf(float f) {
    union { float f; unsigned int u; } c; c.f = f;
    return (ushort_t)((c.u + 0x8000u) >> 16);
}
__device__ __forceinline__ unsigned int pkbf(float a, float b) {
    __hip_bfloat162 h = __float22bfloat162_rn(make_float2(a, b));
    unsigned int u; __builtin_memcpy(&u, &h, 4); return u;
}
__device__ __forceinline__ unsigned int pkbf_asm(float a, float b) {
    unsigned int d;
    asm("v_cvt_pk_bf16_f32 %0, %1, %2" : "=v"(d) : "v"(a), "v"(b));
    return d;
}
__device__ __forceinline__ float exp2_raw(float x) {
    float d; asm("v_exp_f32 %0, %1" : "=v"(d) : "v"(x)); return d;
}
__device__ __forceinline__ float max3f(float a, float b, float c) {
    float d; asm("v_max3_f32 %0, %1, %2, %3" : "=v"(d) : "v"(a), "v"(b), "v"(c)); return d;
}
__device__ __forceinline__ void gld16(const ushort_t* g, ushort_t* l) {
    __builtin_amdgcn_global_load_lds(
        (const __attribute__((address_space(1))) unsigned int*)g,
        (__attribute__((address_space(3))) unsigned int*)l, 16, 0, 0);
}

// ---------------- pre-convert: 4 weight matrices (y<4) + 3 X inputs -----------------
__global__ __launch_bounds__(256) void cvt_all(
    const float* __restrict__ w0, const float* __restrict__ w1,
    const float* __restrict__ w2, const float* __restrict__ w3,
    const float* __restrict__ x0, const float* __restrict__ x1,
    const float* __restrict__ x2,
    ushort_t* __restrict__ o0, ushort_t* __restrict__ o1,
    ushort_t* __restrict__ o2, ushort_t* __restrict__ o3,
    ushort_t* __restrict__ xb)
{
    const int y = blockIdx.y;
    if (y < 4) {
        const float* s; ushort_t* d;
        switch (y) {
            case 0: s = w0; d = o0; break;
            case 1: s = w1; d = o1; break;
            case 2: s = w2; d = o2; break;
            default: s = w3; d = o3; break;
        }
        int i = (blockIdx.x * 256 + threadIdx.x) * 4;
        float4v v = *(const float4v*)(s + i);
        uint2 o; o.x = pkbf(v[0], v[1]); o.y = pkbf(v[2], v[3]);
        *(uint2*)(d + i) = o;
    } else {
        const int m = y - 4;
        const float* s = (m == 0) ? x0 : (m == 1) ? x1 : x2;
        ushort_t* d = xb + (size_t)m * (BSZ * SEQ * DIMN);
        size_t base = (size_t)blockIdx.x * 4096;
#pragma unroll
        for (int j = 0; j < 4; ++j) {
            size_t i = base + j * 1024 + threadIdx.x * 4;
            float4v v = *(const float4v*)(s + i);
            uint2 o; o.x = pkbf(v[0], v[1]); o.y = pkbf(v[2], v[3]);
            *(uint2*)(d + i) = o;
        }
    }
}

// ---------------- QKV GEMM (fast): all-bf16, gld16, R10: + XCD swizzle --------------
// R3-proven 2-barrier body. Grid 768 (1-D). Bijective XCD swizzle (768%8==0):
// each XCD gets 96 contiguous tile-ids = 4 m-panels x all 24 (z,n) -> A panels
// fetched once per XCD L2 instead of 8x across XCDs. Cuts L2-fill ~2-3x (T1).
__global__ __launch_bounds__(256) void gemm_qkv_fast(
    const ushort_t* __restrict__ Xb,
    const ushort_t* __restrict__ Wq, const ushort_t* __restrict__ Wk, const ushort_t* __restrict__ Wv,
    const float* __restrict__ qb, const float* __restrict__ kb, const float* __restrict__ vb,
    ushort_t* __restrict__ Qp, ushort_t* __restrict__ Kp, ushort_t* __restrict__ VpT)
{
    __shared__ __align__(16) ushort_t As[128 * 64];
    __shared__ __align__(16) ushort_t Bs[128 * 64];
    const int tid  = threadIdx.x;
    const int lane = tid & 63;
    const int w    = tid >> 6;
    const int wm   = w >> 1, wn = w & 1;
    const int quad = lane >> 4;
    const int l16  = lane & 15;
    const int sw   = l16 & 7;

    // XCD-aware bijective swizzle: nwg=768, chunk=96 per XCD
    const int orig = blockIdx.x;
    const int swz  = (orig & 7) * 96 + (orig >> 3);
    const int bx   = swz % 24;
    const int by   = swz / 24;

    const int mBase = by * 128;
    const int nGlob = bx * 128;
    const int z     = nGlob >> 10;
    const int nBase = nGlob & 1023;
    const ushort_t* A    = Xb + (size_t)z * (BSZ * SEQ * DIMN);
    const ushort_t* W    = (z == 0) ? Wq : (z == 1) ? Wk : Wv;
    const float*    bias = (z == 0) ? qb : (z == 1) ? kb : vb;

    const int srow = tid >> 3;   // 0..31
    const int sc   = tid & 7;

    float4v acc[4][4];
    const float4v z4 = {0.f, 0.f, 0.f, 0.f};
#pragma unroll
    for (int i = 0; i < 4; ++i)
#pragma unroll
        for (int j = 0; j < 4; ++j) acc[i][j] = z4;

    for (int k0 = 0; k0 < 1024; k0 += 64) {
#pragma unroll
        for (int itq = 0; itq < 4; ++itq) {
            int row = itq * 32 + srow;
            int colsw = (sc ^ (row & 7)) * 8;
            gld16(A + (size_t)(mBase + row) * 1024 + k0 + colsw, &As[(itq * 32 + w * 8) * 64]);
            gld16(W + (size_t)(nBase + row) * 1024 + k0 + colsw, &Bs[(itq * 32 + w * 8) * 64]);
        }
        __syncthreads();   // drains vmcnt -> staged tiles visible

#pragma unroll
        for (int ksub = 0; ksub < 2; ++ksub) {
            short8 af[4], bf[4];
#pragma unroll
            for (int mt = 0; mt < 4; ++mt)
                af[mt] = *(const short8*)&As[(wm * 64 + mt * 16 + l16) * 64 + ((ksub * 4 + quad) ^ sw) * 8];
#pragma unroll
            for (int nt = 0; nt < 4; ++nt)
                bf[nt] = *(const short8*)&Bs[(wn * 64 + nt * 16 + l16) * 64 + ((ksub * 4 + quad) ^ sw) * 8];
#pragma unroll
            for (int mt = 0; mt < 4; ++mt)
#pragma unroll
                for (int nt = 0; nt < 4; ++nt)
                    acc[mt][nt] = __builtin_amdgcn_mfma_f32_16x16x32_bf16(af[mt], bf[nt], acc[mt][nt], 0, 0, 0);
        }
        __syncthreads();   // all reads done before next iter's gld writes
    }

    const float scale = (z == 0) ? 0.125f * LOG2E : 1.0f;
    if (z < 2) {
        ushort_t* C = (z == 0) ? Qp : Kp;
#pragma unroll
        for (int mt = 0; mt < 4; ++mt)
#pragma unroll
            for (int nt = 0; nt < 4; ++nt) {
                int colg = nBase + wn * 64 + nt * 16 + l16;
                float bv = bias[colg];
#pragma unroll
                for (int r = 0; r < 4; ++r) {
                    int rowg = mBase + wm * 64 + mt * 16 + quad * 4 + r;
                    C[(size_t)rowg * 1024 + colg] = f2bf((acc[mt][nt][r] + bv) * scale);
                }
            }
    } else {
#pragma unroll
        for (int mt = 0; mt < 4; ++mt)
#pragma unroll
            for (int nt = 0; nt < 4; ++nt) {
                int n = nBase + wn * 64 + nt * 16 + l16;
                int hh = n >> 6, d = n & 63;
                float bv = bias[n];
                int rowg = mBase + wm * 64 + mt * 16 + quad * 4;
                int b = rowg >> 11, s = rowg & 2047;
                uint2 pk;
                pk.x = pkbf(acc[mt][nt][0] + bv, acc[mt][nt][1] + bv);
                pk.y = pkbf(acc[mt][nt][2] + bv, acc[mt][nt][3] + bv);
                *(uint2*)&VpT[(((size_t)(b * 16 + hh) * 64 + d) << 11) + s] = pk;
            }
    }
}

// ---------------- QKV GEMM (fallback, no Xb): f32-A reg-staged hybrid ---------------
__global__ __launch_bounds__(256) void gemm_qkv_hyb(
    const float* __restrict__ xq, const float* __restrict__ xk, const float* __restrict__ xv,
    const ushort_t* __restrict__ Wq, const ushort_t* __restrict__ Wk, const ushort_t* __restrict__ Wv,
    const float* __restrict__ qb, const float* __restrict__ kb, const float* __restrict__ vb,
    ushort_t* __restrict__ Qp, ushort_t* __restrict__ Kp, ushort_t* __restrict__ VpT)
{
    __shared__ __align__(16) ushort_t As[128 * 64];
    __shared__ __align__(16) ushort_t Bs[128 * 64];
    const int tid  = threadIdx.x;
    const int lane = tid & 63;
    const int w    = tid >> 6;
    const int wm   = w >> 1, wn = w & 1;
    const int quad = lane >> 4;
    const int l16  = lane & 15;
    const int sw   = l16 & 7;
    const int mBase = blockIdx.y * 128;
    const int nGlob = blockIdx.x * 128;
    const int z     = nGlob >> 10;
    const int nBase = nGlob & 1023;
    const float*    A    = (z == 0) ? xq : (z == 1) ? xk : xv;
    const ushort_t* W    = (z == 0) ? Wq : (z == 1) ? Wk : Wv;
    const float*    bias = (z == 0) ? qb : (z == 1) ? kb : vb;

    const int srow = tid >> 3;
    const int sc   = tid & 7;

    float4v acc[4][4];
    const float4v z4 = {0.f, 0.f, 0.f, 0.f};
#pragma unroll
    for (int i = 0; i < 4; ++i)
#pragma unroll
        for (int j = 0; j < 4; ++j) acc[i][j] = z4;

    for (int k0 = 0; k0 < 1024; k0 += 64) {
#pragma unroll
        for (int itq = 0; itq < 4; ++itq) {
            int row = itq * 32 + srow;
            int colsw = (sc ^ (row & 7)) * 8;
            gld16(W + (size_t)(nBase + row) * 1024 + k0 + colsw, &Bs[(itq * 32 + w * 8) * 64]);
        }
#pragma unroll
        for (int it = 0; it < 4; ++it) {
            int c = it * 256 + tid, row = c >> 3, col8 = c & 7;
            const float* g = A + (size_t)(mBase + row) * 1024 + k0 + col8 * 8;
            float4v a0 = *(const float4v*)g;
            float4v a1 = *(const float4v*)(g + 4);
            uint4 ua;
            ua.x = pkbf(a0[0], a0[1]); ua.y = pkbf(a0[2], a0[3]);
            ua.z = pkbf(a1[0], a1[1]); ua.w = pkbf(a1[2], a1[3]);
            *(uint4*)&As[row * 64 + ((col8 ^ (row & 7)) * 8)] = ua;
        }
        __syncthreads();

#pragma unroll
        for (int ksub = 0; ksub < 2; ++ksub) {
            short8 af[4], bf[4];
#pragma unroll
            for (int mt = 0; mt < 4; ++mt)
                af[mt] = *(const short8*)&As[(wm * 64 + mt * 16 + l16) * 64 + ((ksub * 4 + quad) ^ sw) * 8];
#pragma unroll
            for (int nt = 0; nt < 4; ++nt)
                bf[nt] = *(const short8*)&Bs[(wn * 64 + nt * 16 + l16) * 64 + ((ksub * 4 + quad) ^ sw) * 8];
#pragma unroll
            for (int mt = 0; mt < 4; ++mt)
#pragma unroll
                for (int nt = 0; nt < 4; ++nt)
                    acc[mt][nt] = __builtin_amdgcn_mfma_f32_16x16x32_bf16(af[mt], bf[nt], acc[mt][nt], 0, 0, 0);
        }
        __syncthreads();
    }

    const float scale = (z == 0) ? 0.125f * LOG2E : 1.0f;
    if (z < 2) {
        ushort_t* C = (z == 0) ? Qp : Kp;
#pragma unroll
        for (int mt = 0; mt < 4; ++mt)
#pragma unroll
            for (int nt = 0; nt < 4; ++nt) {
                int colg = nBase + wn * 64 + nt * 16 + l16;
                float bv = bias[colg];
#pragma unroll
                for (int r = 0; r < 4; ++r) {
                    int rowg = mBase + wm * 64 + mt * 16 + quad * 4 + r;
                    C[(size_t)rowg * 1024 + colg] = f2bf((acc[mt][nt][r] + bv) * scale);
                }
            }
    } else {
#pragma unroll
        for (int mt = 0; mt < 4; ++mt)
#pragma unroll
            for (int nt = 0; nt < 4; ++nt) {
                int n = nBase + wn * 64 + nt * 16 + l16;
                int hh = n >> 6, d = n & 63;
                float bv = bias[n];
                int rowg = mBase + wm * 64 + mt * 16 + quad * 4;
                int b = rowg >> 11, s = rowg & 2047;
                uint2 pk;
                pk.x = pkbf(acc[mt][nt][0] + bv, acc[mt][nt][1] + bv);
                pk.y = pkbf(acc[mt][nt][2] + bv, acc[mt][nt][3] + bv);
                *(uint2*)&VpT[(((size_t)(b * 16 + hh) * 64 + d) << 11) + s] = pk;
            }
    }
}

// ---------------- O GEMM: 128x64, BK=64 — gld16 + swizzled LDS + XCD swizzle --------
__global__ __launch_bounds__(256) void gemm_o(
    const ushort_t* __restrict__ A, const ushort_t* __restrict__ W,
    const float* __restrict__ bias, float* __restrict__ C)
{
    __shared__ __align__(16) ushort_t As[128 * 64];
    __shared__ __align__(16) ushort_t Bs[64 * 64];
    const int tid  = threadIdx.x;
    const int lane = tid & 63;
    const int w    = tid >> 6;
    const int wm   = w & 1, wn = w >> 1;
    const int quad = lane >> 4;
    const int l16  = lane & 15;
    const int sw   = l16 & 7;

    // XCD-aware bijective swizzle: nwg=512, chunk=64 per XCD
    const int orig = blockIdx.x;
    const int swz  = (orig & 7) * 64 + (orig >> 3);
    const int nBase = (swz & 15) * 64;
    const int mBase = (swz >> 4) * 128;

    const int srow = tid >> 3;   // 0..31
    const int sc   = tid & 7;

    float4v acc[4][2];
    const float4v z4 = {0.f, 0.f, 0.f, 0.f};
#pragma unroll
    for (int mt = 0; mt < 4; ++mt)
#pragma unroll
        for (int nt = 0; nt < 2; ++nt) acc[mt][nt] = z4;

    for (int k0 = 0; k0 < 1024; k0 += 64) {
#pragma unroll
        for (int itq = 0; itq < 4; ++itq) {
            int row = itq * 32 + srow;
            gld16(A + (size_t)(mBase + row) * 1024 + k0 + ((sc ^ (row & 7)) * 8),
                  &As[(itq * 32 + w * 8) * 64]);
        }
#pragma unroll
        for (int itq = 0; itq < 2; ++itq) {
            int row = itq * 32 + srow;
            gld16(W + (size_t)(nBase + row) * 1024 + k0 + ((sc ^ (row & 7)) * 8),
                  &Bs[(itq * 32 + w * 8) * 64]);
        }
        __syncthreads();

#pragma unroll
        for (int ksub = 0; ksub < 2; ++ksub) {
            short8 af[4], bf[2];
#pragma unroll
            for (int mt = 0; mt < 4; ++mt)
                af[mt] = *(const short8*)&As[(wm * 64 + mt * 16 + l16) * 64 + ((ksub * 4 + quad) ^ sw) * 8];
#pragma unroll
            for (int nt = 0; nt < 2; ++nt)
                bf[nt] = *(const short8*)&Bs[(wn * 32 + nt * 16 + l16) * 64 + ((ksub * 4 + quad) ^ sw) * 8];
#pragma unroll
            for (int mt = 0; mt < 4; ++mt)
#pragma unroll
                for (int nt = 0; nt < 2; ++nt)
                    acc[mt][nt] = __builtin_amdgcn_mfma_f32_16x16x32_bf16(af[mt], bf[nt], acc[mt][nt], 0, 0, 0);
        }
        __syncthreads();
    }

#pragma unroll
    for (int mt = 0; mt < 4; ++mt)
#pragma unroll
        for (int nt = 0; nt < 2; ++nt) {
            int colg = nBase + wn * 32 + nt * 16 + l16;
            float bv = bias[colg];
#pragma unroll
            for (int r = 0; r < 4; ++r) {
                int rowg = mBase + wm * 64 + mt * 16 + quad * 4 + r;
                C[(size_t)rowg * 1024 + colg] = acc[mt][nt][r] + bv;
            }
        }
}

// ---------------- fused flash attention: R7-exact (proven 53.7 us) ------------------
__global__ __launch_bounds__(512) void attn_kernel(
    const ushort_t* __restrict__ Qp, const ushort_t* __restrict__ Kp,
    const ushort_t* __restrict__ VpT, const int* __restrict__ mask,
    ushort_t* __restrict__ Cp)
{
    __shared__ __align__(16) ushort_t Ps[2][128 * 64]; // P ping-pong; Ps[0] = Q staging
    __shared__ __align__(16) ushort_t Ks[2][64 * 64];  // K double buffer
    __shared__ __align__(16) ushort_t Vt[3][64 * 64];  // V^T triple buffer [dim][key]
    __shared__ int s_mok[8];

    const int tid  = threadIdx.x;
    const int lane = tid & 63;
    const int w    = tid >> 6;          // 0..7
    const int quad = lane >> 4;
    const int l16  = lane & 15;
    const int sw   = l16 & 7;           // per-lane XOR swizzle key for reads
    const int b    = blockIdx.x >> 4;
    const int h    = blockIdx.x & 15;
    const int q0   = blockIdx.y * 128;

    const int srow = tid >> 3;          // staging row 0..63
    const int sc   = tid & 7;           // staging 16B chunk 0..7
    const int gsc  = (sc ^ (srow & 7)) * 8;  // pre-swizzled global source col (elems)
    const ushort_t* Vbase = VpT + ((size_t)(b * 16 + h) * 64) * 2048;
    const ushort_t* Kbase = Kp + (size_t)b * SEQ * DIMN + h * DH;
    const ushort_t* Qbase = Qp + (size_t)(b * SEQ + q0) * DIMN + h * DH;

    // block-level mask scan: is the whole key row unmasked?
    {
        int m0 = mask[b * SEQ + tid];
        int m1 = mask[b * SEQ + 512 + tid];
        int m2 = mask[b * SEQ + 1024 + tid];
        int m3 = mask[b * SEQ + 1536 + tid];
        int ok = __all((m0 != 0) & (m1 != 0) & (m2 != 0) & (m3 != 0));
        if (lane == 0) s_mok[w] = ok;
    }

    // stage Q (128x64) into Ps[0]
#pragma unroll
    for (int it2 = 0; it2 < 2; ++it2) {
        int row = it2 * 64 + srow;
        gld16(Qbase + (size_t)row * DIMN + ((sc ^ (row & 7)) * 8),
              &Ps[0][(it2 * 64 + w * 8) * 64]);
    }
    // K/V tile 0
    gld16(Kbase + (size_t)srow * DIMN + gsc, &Ks[0][w * 512]);
    gld16(Vbase + (size_t)srow * 2048 + gsc, &Vt[0][w * 512]);
    __syncthreads();   // drains vmcnt: Q/K0/V0 in LDS, s_mok visible

    const int mall = s_mok[0] & s_mok[1] & s_mok[2] & s_mok[3]
                   & s_mok[4] & s_mok[5] & s_mok[6] & s_mok[7];

    short8 bq[2];
#pragma unroll
    for (int ks = 0; ks < 2; ++ks)
        bq[ks] = *(const short8*)&Ps[0][(w * 16 + l16) * 64 + ((4 * ks + quad) ^ sw) * 8];

    const float4v z4 = {0.f, 0.f, 0.f, 0.f};
    float4v Oacc[4];   // O^T: [dim vt*16+quad*4+r][qrow l16]
#pragma unroll
    for (int vt = 0; vt < 4; ++vt) Oacc[vt] = z4;
    float4v Lacc = z4;
    float mrow = 0.0f;        // per-qrow running max (log2 domain)
    float4v mneg4 = z4;       // = {-mrow}; C-init of QK MFMA supplies the -m bias

    short8 ones;
#pragma unroll
    for (int j = 0; j < 8; ++j) ones[j] = (short)0x3F80;

    const int NT = SEQ / 64;
    const int prow = (w * 16 + l16) * 64;   // wave-private P/V row base

    // ---------------- peeled iter 0: QK(0) + softmax(0) + pack, no PV ----------------
    {
        gld16(Kbase + (size_t)(64 + srow) * DIMN + gsc, &Ks[1][w * 512]);
        gld16(Vbase + (size_t)srow * 2048 + 64 + gsc, &Vt[1][w * 512]);

        float4v Sv[4];
        __builtin_amdgcn_s_setprio(1);
#pragma unroll
        for (int kt = 0; kt < 4; ++kt) {
            short8 ak = *(const short8*)&Ks[0][(kt * 16 + l16) * 64 + (quad ^ sw) * 8];
            Sv[kt] = __builtin_amdgcn_mfma_f32_16x16x32_bf16(ak, bq[0], mneg4, 0, 0, 0);
        }
#pragma unroll
        for (int kt = 0; kt < 4; ++kt) {
            short8 ak = *(const short8*)&Ks[0][(kt * 16 + l16) * 64 + ((4 + quad) ^ sw) * 8];
            Sv[kt] = __builtin_amdgcn_mfma_f32_16x16x32_bf16(ak, bq[1], Sv[kt], 0, 0, 0);
        }
        __builtin_amdgcn_s_setprio(0);

        if (!mall) {
#pragma unroll
            for (int kt = 0; kt < 4; ++kt) {
                int4 mv = *(const int4*)(mask + b * SEQ + kt * 16 + quad * 4);
#pragma unroll
                for (int r = 0; r < 4; ++r) {
                    int m = (r == 0) ? mv.x : (r == 1) ? mv.y : (r == 2) ? mv.z : mv.w;
                    Sv[kt][r] += (m == 0) ? -1e30f : 0.0f;
                }
            }
        }

        float a0 = max3f(Sv[0][0], Sv[0][1], Sv[0][2]);
        float a1 = max3f(Sv[0][3], Sv[1][0], Sv[1][1]);
        float a2 = max3f(Sv[1][2], Sv[1][3], Sv[2][0]);
        float a3 = max3f(Sv[2][1], Sv[2][2], Sv[2][3]);
        float a4 = max3f(Sv[3][0], Sv[3][1], Sv[3][2]);
        float b0 = max3f(a0, a1, Sv[3][3]);
        float b1 = max3f(a2, a3, a4);
        float mx = fmaxf(b0, b1);
        mx = fmaxf(mx, __shfl_xor(mx, 16));
        mx = fmaxf(mx, __shfl_xor(mx, 32));
        if (!__all(mx <= 8.0f)) {
            float d = fmaxf(mx, 0.0f);
            float alpha = exp2_raw(-d);
            mrow += d;
#pragma unroll
            for (int vt = 0; vt < 4; ++vt) Oacc[vt] *= alpha;
            Lacc *= alpha;
#pragma unroll
            for (int kt = 0; kt < 4; ++kt)
#pragma unroll
                for (int r = 0; r < 4; ++r) Sv[kt][r] -= d;
            mneg4[0] = -mrow; mneg4[1] = -mrow; mneg4[2] = -mrow; mneg4[3] = -mrow;
        }
#pragma unroll
        for (int kt = 0; kt < 4; ++kt)
#pragma unroll
            for (int r = 0; r < 4; ++r) Sv[kt][r] = exp2_raw(Sv[kt][r]);

#pragma unroll
        for (int kt = 0; kt < 4; ++kt) {
            uint2 pk;
            pk.x = pkbf_asm(Sv[kt][0], Sv[kt][1]);
            pk.y = pkbf_asm(Sv[kt][2], Sv[kt][3]);
            int chunk = (2 * kt + (quad >> 1)) ^ sw;
            *(uint2*)&Ps[0][prow + chunk * 8 + (quad & 1) * 4] = pk;
        }
        __syncthreads();   // drains K1/V1 prefetch; P(0) visible (wave-private anyway)
    }

    // rotating V pointers: at loop iter t, vRd=V(t-1), vCur=V(t), vWr=slot for V(t+1)
    ushort_t* vRd  = Vt[0];
    ushort_t* vCur = Vt[1];
    ushort_t* vWr  = Vt[2];

#pragma unroll 2
    for (int t = 1; t < NT; ++t) {
        const int kt0 = t * 64;

        // prefetch tile t+1
        if (t + 1 < NT) {
            gld16(Kbase + (size_t)(kt0 + 64 + srow) * DIMN + gsc, &Ks[(t + 1) & 1][w * 512]);
            gld16(Vbase + (size_t)srow * 2048 + kt0 + 64 + gsc, vWr + w * 512);
        }

        // ---- fused MFMA cluster: QK(t) then PV(t-1) ----
        float4v Sv[4];
        __builtin_amdgcn_s_setprio(1);
#pragma unroll
        for (int kt = 0; kt < 4; ++kt) {
            short8 ak = *(const short8*)&Ks[t & 1][(kt * 16 + l16) * 64 + (quad ^ sw) * 8];
            Sv[kt] = __builtin_amdgcn_mfma_f32_16x16x32_bf16(ak, bq[0], mneg4, 0, 0, 0);
        }
#pragma unroll
        for (int kt = 0; kt < 4; ++kt) {
            short8 ak = *(const short8*)&Ks[t & 1][(kt * 16 + l16) * 64 + ((4 + quad) ^ sw) * 8];
            Sv[kt] = __builtin_amdgcn_mfma_f32_16x16x32_bf16(ak, bq[1], Sv[kt], 0, 0, 0);
        }
        // PV(t-1): P from Ps[(t-1)&1], V from vRd (= V(t-1))
#pragma unroll
        for (int ks = 0; ks < 2; ++ks) {
            short8 bp = *(const short8*)&Ps[(t - 1) & 1][prow + ((4 * ks + quad) ^ sw) * 8];
            Lacc = __builtin_amdgcn_mfma_f32_16x16x32_bf16(ones, bp, Lacc, 0, 0, 0);
#pragma unroll
            for (int vt = 0; vt < 4; ++vt) {
                short8 av = *(const short8*)(vRd + (vt * 16 + l16) * 64 + ((4 * ks + quad) ^ sw) * 8);
                Oacc[vt] = __builtin_amdgcn_mfma_f32_16x16x32_bf16(av, bp, Oacc[vt], 0, 0, 0);
            }
        }
        __builtin_amdgcn_s_setprio(0);

        // additive mask (rare path)
        if (!mall) {
#pragma unroll
            for (int kt = 0; kt < 4; ++kt) {
                int4 mv = *(const int4*)(mask + b * SEQ + kt0 + kt * 16 + quad * 4);
#pragma unroll
                for (int r = 0; r < 4; ++r) {
                    int m = (r == 0) ? mv.x : (r == 1) ? mv.y : (r == 2) ? mv.z : mv.w;
                    Sv[kt][r] += (m == 0) ? -1e30f : 0.0f;
                }
            }
        }

        // softmax(t) — O already holds PV(0..t-1), so rescale here is correct
        float a0 = max3f(Sv[0][0], Sv[0][1], Sv[0][2]);
        float a1 = max3f(Sv[0][3], Sv[1][0], Sv[1][1]);
        float a2 = max3f(Sv[1][2], Sv[1][3], Sv[2][0]);
        float a3 = max3f(Sv[2][1], Sv[2][2], Sv[2][3]);
        float a4 = max3f(Sv[3][0], Sv[3][1], Sv[3][2]);
        float b0 = max3f(a0, a1, Sv[3][3]);
        float b1 = max3f(a2, a3, a4);
        float mx = fmaxf(b0, b1);
        mx = fmaxf(mx, __shfl_xor(mx, 16));
        mx = fmaxf(mx, __shfl_xor(mx, 32));
        if (!__all(mx <= 8.0f)) {
            float d = fmaxf(mx, 0.0f);
            float alpha = exp2_raw(-d);
            mrow += d;
#pragma unroll
            for (int vt = 0; vt < 4; ++vt) Oacc[vt] *= alpha;
            Lacc *= alpha;
#pragma unroll
            for (int kt = 0; kt < 4; ++kt)
#pragma unroll
                for (int r = 0; r < 4; ++r) Sv[kt][r] -= d;
            mneg4[0] = -mrow; mneg4[1] = -mrow; mneg4[2] = -mrow; mneg4[3] = -mrow;
        }
#pragma unroll
        for (int kt = 0; kt < 4; ++kt)
#pragma unroll
            for (int r = 0; r < 4; ++r) Sv[kt][r] = exp2_raw(Sv[kt][r]);

        // pack P(t) -> Ps[t&1] (wave-private rows; PV next iter reads it)
#pragma unroll
        for (int kt = 0; kt < 4; ++kt) {
            uint2 pk;
            pk.x = pkbf_asm(Sv[kt][0], Sv[kt][1]);
            pk.y = pkbf_asm(Sv[kt][2], Sv[kt][3]);
            int chunk = (2 * kt + (quad >> 1)) ^ sw;
            *(uint2*)&Ps[t & 1][prow + chunk * 8 + (quad & 1) * 4] = pk;
        }

        __syncthreads();   // drains prefetch vmcnt + separates K/V buffer roles

        // rotate V buffers
        ushort_t* tmp = vRd; vRd = vCur; vCur = vWr; vWr = tmp;
    }

    // ---------------- epilogue: PV(NT-1) then normalize + store ----------------------
#pragma unroll
    for (int ks = 0; ks < 2; ++ks) {
        short8 bp = *(const short8*)&Ps[(NT - 1) & 1][prow + ((4 * ks + quad) ^ sw) * 8];
        Lacc = __builtin_amdgcn_mfma_f32_16x16x32_bf16(ones, bp, Lacc, 0, 0, 0);
#pragma unroll
        for (int vt = 0; vt < 4; ++vt) {
            short8 av = *(const short8*)(vRd + (vt * 16 + l16) * 64 + ((4 * ks + quad) ^ sw) * 8);
            Oacc[vt] = __builtin_amdgcn_mfma_f32_16x16x32_bf16(av, bp, Oacc[vt], 0, 0, 0);
        }
    }

    float inv = 1.0f / Lacc[0];
    int row = q0 + w * 16 + l16;
#pragma unroll
    for (int vt = 0; vt < 4; ++vt) {
        uint2 pk;
        pk.x = pkbf_asm(Oacc[vt][0] * inv, Oacc[vt][1] * inv);
        pk.y = pkbf_asm(Oacc[vt][2] * inv, Oacc[vt][3] * inv);
        *(uint2*)&Cp[(size_t)(b * SEQ + row) * DIMN + h * DH + vt * 16 + quad * 4] = pk;
    }
}

extern "C" void kernel_launch(void* const* d_in, const int* in_sizes, int n_in,
                              void* d_out, int out_size, void* d_ws, size_t ws_size,
                              hipStream_t stream) {
    const float* x_q = (const float*)d_in[0];
    const float* x_k = (const float*)d_in[1];
    const float* x_v = (const float*)d_in[2];
    const int*   msk = (const int*)d_in[3];
    const float* q_w = (const float*)d_in[4];
    const float* q_b = (const float*)d_in[5];
    const float* k_w = (const float*)d_in[6];
    const float* k_b = (const float*)d_in[7];
    const float* v_w = (const float*)d_in[8];
    const float* v_b = (const float*)d_in[9];
    const float* o_w = (const float*)d_in[10];
    const float* o_b = (const float*)d_in[11];
    float* out = (float*)d_out;

    const size_t NEL = (size_t)BSZ * SEQ * DIMN;   // 4 Mi
    const size_t WEL = (size_t)DIMN * DIMN;        // 1 Mi
    // layout: Qp | Kp | VpT | Wq Wk Wv Wo | Xb (fast path)  = 56 MiB
    ushort_t* Qp  = (ushort_t*)d_ws;
    ushort_t* Kp  = Qp + NEL;
    ushort_t* VpT = Kp + NEL;
    ushort_t* Wq  = VpT + NEL;
    ushort_t* Wk  = Wq + WEL;
    ushort_t* Wv  = Wk + WEL;
    ushort_t* Wo  = Wv + WEL;
    ushort_t* Xb  = Wo + WEL;          // 3*NEL elems = 24 MiB
    ushort_t* Cp  = Qp;   // aliases Qp (read-before-write, per-block disjoint regions)

    const bool fast = ws_size >= ((size_t)56 << 20);
    if (fast) {
        cvt_all<<<dim3(1024, 7), 256, 0, stream>>>(q_w, k_w, v_w, o_w, x_q, x_k, x_v,
                                                   Wq, Wk, Wv, Wo, Xb);
        gemm_qkv_fast<<<dim3(768), 256, 0, stream>>>(Xb, Wq, Wk, Wv,
                                                     q_b, k_b, v_b, Qp, Kp, VpT);
    } else {
        cvt_all<<<dim3(1024, 4), 256, 0, stream>>>(q_w, k_w, v_w, o_w, x_q, x_k, x_v,
                                                   Wq, Wk, Wv, Wo, Xb);
        gemm_qkv_hyb<<<dim3(24, 32), 256, 0, stream>>>(x_q, x_k, x_v, Wq, Wk, Wv,
                                                       q_b, k_b, v_b, Qp, Kp, VpT);
    }
    attn_kernel<<<dim3(BSZ * NH, SEQ / 128), 512, 0, stream>>>(Qp, Kp, VpT, msk, Cp);
    gemm_o<<<dim3(512), 256, 0, stream>>>(Cp, Wo, o_b, out);
}